// Round 4
// baseline (55.739 us; speedup 1.0000x reference)
//
#include <hip/hip_runtime.h>
#include <cmath>

// ---------------------------------------------------------------------------
// NeighborAdjustingLoss v5: v4 + ballot-compaction gather (no LDS atomics).
// The gather of ~93 candidates used ~93 serialized same-address LDS
// atomicAdds + dependent LDS writes per block inside the latency-bound
// streaming phase (v2 evidence: 77us at 1.3MB HBM traffic, VALUBusy 20%).
// Replaced with __ballot/__popcll counting (pass A, 1 barrier/iter) and a
// deterministic mbcnt-prefix write pass. cand[] order changes; ranks are
// exact all-pairs u64 comparisons -> output bit-identical.
// B=4096 (sim BxB), M=8192 (mem BxM), k<=63, fp32.
// ---------------------------------------------------------------------------

#define CAP 256    // candidate capacity; expected ~93 for N(0,1) rows (>17 sigma)
#define MAXIT 40   // u32-key bisection bound (1 pass in practice)

__device__ inline float wave_max_f(float x) {
#pragma unroll
    for (int off = 32; off > 0; off >>= 1) x = fmaxf(x, __shfl_xor(x, off, 64));
    return x;
}
__device__ inline float wave_min_f(float x) {
#pragma unroll
    for (int off = 32; off > 0; off >>= 1) x = fminf(x, __shfl_xor(x, off, 64));
    return x;
}
__device__ inline float wave_sum_f(float x) {
#pragma unroll
    for (int off = 32; off > 0; off >>= 1) x += __shfl_xor(x, off, 64);
    return x;
}
__device__ inline unsigned int wave_min_u32(unsigned int x) {
#pragma unroll
    for (int off = 32; off > 0; off >>= 1) {
        unsigned int o = (unsigned int)__shfl_xor((int)x, off, 64);
        x = (o < x) ? o : x;
    }
    return x;
}

// order-preserving float<->uint key
__device__ inline unsigned int f_to_key(float f) {
    unsigned int u = __float_as_uint(f);
    return u ^ ((u & 0x80000000u) ? 0xFFFFFFFFu : 0x80000000u);
}
__device__ inline float key_to_f(unsigned int key) {
    unsigned int u = key ^ ((key & 0x80000000u) ? 0x80000000u : 0xFFFFFFFFu);
    return __uint_as_float(u);
}

// bits set among lanes strictly below mine
__device__ inline unsigned int lane_prefix(unsigned long long mask) {
    return __builtin_amdgcn_mbcnt_hi((unsigned int)(mask >> 32),
           __builtin_amdgcn_mbcnt_lo((unsigned int)mask, 0u));
}

// ---- centrality = row-mean of memory bank (8 loads in flight) ----
__global__ __launch_bounds__(256)
void cent_kernel(const float* __restrict__ mem, float* __restrict__ cent, int M) {
    __shared__ float s[4];
    const int row = blockIdx.x;
    const float4* p = (const float4*)(mem + (size_t)row * M);
    const int n4 = M >> 2;
    float acc = 0.0f;
    int i = threadIdx.x;
    for (; i + 1792 < n4; i += 2048) {
        float4 q0 = p[i], q1 = p[i + 256], q2 = p[i + 512], q3 = p[i + 768];
        float4 q4 = p[i + 1024], q5 = p[i + 1280], q6 = p[i + 1536], q7 = p[i + 1792];
        acc += ((q0.x + q0.y) + (q0.z + q0.w)) + ((q1.x + q1.y) + (q1.z + q1.w))
             + ((q2.x + q2.y) + (q2.z + q2.w)) + ((q3.x + q3.y) + (q3.z + q3.w))
             + ((q4.x + q4.y) + (q4.z + q4.w)) + ((q5.x + q5.y) + (q5.z + q5.w))
             + ((q6.x + q6.y) + (q6.z + q6.w)) + ((q7.x + q7.y) + (q7.z + q7.w));
    }
    for (; i < n4; i += 256) {
        float4 q = p[i];
        acc += (q.x + q.y) + (q.z + q.w);
    }
    acc = wave_sum_f(acc);
    const int lane = threadIdx.x & 63, wid = threadIdx.x >> 6;
    if (lane == 0) s[wid] = acc;
    __syncthreads();
    if (threadIdx.x == 0) cent[row] = (s[0] + s[1] + s[2] + s[3]) / (float)M;
}

// ---- per-row loss -> per_row[row]. One 256-thread block per row.
//      Requires B==4096, k<=63. ----
__global__ __launch_bounds__(256)
void row_loss_kernel(const float* __restrict__ sim,
                     const float* __restrict__ cent,
                     const int* __restrict__ knn,
                     const float* __restrict__ temp_p,
                     float* __restrict__ per_row, int B) {
    __shared__ __align__(16) unsigned long long cand[CAP];
    __shared__ unsigned long long s_sel[64];
    __shared__ unsigned long long s_p33;
    __shared__ unsigned int s_kmin[4];
    __shared__ float s_cmin[4], s_cmax[4];
    __shared__ float s_cmin2[4], s_cmax2[4];
    __shared__ unsigned int s_wcnt[4];
    __shared__ float s_diag;

    const int row = blockIdx.x, tid = threadIdx.x;
    const int lane = tid & 63, wid = tid >> 6;
    const int   k    = knn[0];
    const float temp = temp_p[0];

    // --- load row (float4-coalesced), order keys; diag -> key 0 ---
    unsigned int keys[16];
    unsigned int kmin = 0xFFFFFFFFu;
    const float4* rp = (const float4*)(sim + (size_t)row * B);
#pragma unroll
    for (int c = 0; c < 4; ++c) {
        float4 q = rp[c * 256 + tid];
        float t[4] = {q.x, q.y, q.z, q.w};
#pragma unroll
        for (int m = 0; m < 4; ++m) {
            const int j = c * 1024 + tid * 4 + m;
            unsigned int key = f_to_key(t[m]);
            if (j == row) { s_diag = t[m]; key = 0u; }
            else if (key < kmin) kmin = key;
            keys[c * 4 + m] = key;
        }
    }
    { unsigned int w = wave_min_u32(kmin); if (lane == 0) s_kmin[wid] = w; }

    // --- bisection: ballot-count candidates (key > keyT) + cent min/max over
    //     non-candidates. No LDS atomics, no cand writes during search.
    //     First-guess threshold 2.0 -> count in [k+1, CAP] w.p. ~1. ---
    unsigned int keyT = f_to_key(2.0f), loK = 0u, hiK = 0xFFFFFFFFu, cnt = 0;
    const unsigned int need = (unsigned int)k + 1u;
    const float4* cp = (const float4*)cent;
    for (int it = 0; it < MAXIT; ++it) {
        float cmin = INFINITY, cmax = -INFINITY;
        unsigned int wvCnt = 0;
#pragma unroll
        for (int c = 0; c < 4; ++c) {
            float4 q = cp[c * 256 + tid];
            float t[4] = {q.x, q.y, q.z, q.w};
#pragma unroll
            for (int m = 0; m < 4; ++m) {
                const unsigned int key = keys[c * 4 + m];
                const bool p = (key > keyT);
                const unsigned long long mask = __ballot(p);
                wvCnt += (unsigned int)__popcll(mask);
                if (!p && key != 0u) {       // diag (key==0) excluded everywhere
                    cmin = fminf(cmin, t[m]);
                    cmax = fmaxf(cmax, t[m]);
                }
            }
        }
        { float a = wave_min_f(cmin), b = wave_max_f(cmax);
          if (lane == 0) { s_cmin[wid] = a; s_cmax[wid] = b; s_wcnt[wid] = wvCnt; } }
        __syncthreads();                    // counts/minmax visible
        cnt = s_wcnt[0] + s_wcnt[1] + s_wcnt[2] + s_wcnt[3];
        if (cnt >= need && cnt <= CAP) break;
        if (it == MAXIT - 1) break;
        if (cnt < need) { hiK = keyT; keyT = loK + ((keyT - loK) >> 1); }
        else            { loK = keyT; keyT = keyT + ((hiK - keyT) >> 1); }
        __syncthreads();                    // WAR: reads done before rewrite
    }

    // --- write pass: deterministic compaction via mbcnt prefix ---
    {
        unsigned int base = 0;
#pragma unroll
        for (int w = 0; w < 4; ++w) if (w < wid) base += s_wcnt[w];
        unsigned int run = 0;
#pragma unroll
        for (int c = 0; c < 4; ++c) {
#pragma unroll
            for (int m = 0; m < 4; ++m) {
                const unsigned int key = keys[c * 4 + m];
                const bool p = (key > keyT);
                const unsigned long long mask = __ballot(p);
                if (p) {
                    const unsigned int pos = base + run + lane_prefix(mask);
                    if (pos < CAP)
                        cand[pos] = ((unsigned long long)key << 32) |
                                    (unsigned long long)(0xFFFFFFFFu -
                                        (unsigned int)(c * 1024 + tid * 4 + m));
                }
                run += (unsigned int)__popcll(mask);
            }
        }
        if (tid == 0) s_p33 = ((unsigned long long)1u) << 32;
        __syncthreads();                    // cand/s_p33 visible
    }

    // --- block-wide exact rank: thread t owns cand[t] (n <= CAP == 256) ---
    {
        const unsigned int n = min(cnt, (unsigned int)CAP);
        const unsigned int uk = (unsigned int)k;
        unsigned long long own = 0ull;
        if ((unsigned int)tid < n) own = cand[tid];
        unsigned int r = 0;
        const ulonglong2* c2 = (const ulonglong2*)cand;   // broadcast b128 reads
        const unsigned int np = n >> 1;
        for (unsigned int o = 0; o < np; ++o) {
            ulonglong2 pr = c2[o];
            r += (pr.x > own) ? 1u : 0u;
            r += (pr.y > own) ? 1u : 0u;
        }
        if (n & 1u) r += (cand[n - 1u] > own) ? 1u : 0u;

        // selected: rank < k; rank == k is the (k+1)-th largest (mx_s);
        // rank >= k candidates re-enter centrality min/max
        float cmin2 = INFINITY, cmax2 = -INFINITY;
        if ((unsigned int)tid < n) {
            if (r < uk) s_sel[r] = own;
            else if (r == uk) s_p33 = own;
            if (r >= uk) {
                const int jj = (int)(0xFFFFFFFFu - (unsigned int)own);
                const float cv = cent[jj];
                cmin2 = fminf(cmin2, cv);
                cmax2 = fmaxf(cmax2, cv);
            }
        }
        cmin2 = wave_min_f(cmin2);
        cmax2 = wave_max_f(cmax2);
        if (lane == 0) { s_cmin2[wid] = cmin2; s_cmax2[wid] = cmax2; }
        __syncthreads();                    // s_sel/s_p33/s_cmin2 visible
    }
    if (wid != 0) return;                   // waves 1-3 done

    // --- wave 0: finale (math identical to validated kernel) ---
    {
        const float mn_c = fminf(
            fminf(fminf(s_cmin2[0], s_cmin2[1]), fminf(s_cmin2[2], s_cmin2[3])),
            fminf(fminf(s_cmin[0], s_cmin[1]), fminf(s_cmin[2], s_cmin[3])));
        const float mx_c = fmaxf(
            fmaxf(fmaxf(s_cmax2[0], s_cmax2[1]), fmaxf(s_cmax2[2], s_cmax2[3])),
            fmaxf(fmaxf(s_cmax[0], s_cmax[1]), fmaxf(s_cmax[2], s_cmax[3])));
        const unsigned int kminb =
            min(min(s_kmin[0], s_kmin[1]), min(s_kmin[2], s_kmin[3]));
        const float mn_s = key_to_f(kminb);
        const float mx_s = key_to_f((unsigned int)(s_p33 >> 32));

        const float sdiag = s_diag;
        const bool  act = (lane < k);
        const unsigned long long sel = act ? s_sel[lane] : 0ull;
        const float sj = act ? key_to_f((unsigned int)(sel >> 32)) : -INFINITY;
        const int   j  = act ? (int)(0xFFFFFFFFu - (unsigned int)sel) : 0;
        const float cj = cent[j];

        float a = -INFINITY;
        if (act) {
            const float ns = (sj - mn_s) / (mx_s - mn_s);
            const float nc = (cj - mn_c) / (mx_c - mn_c);
            a = (ns - nc) * temp;
        }
        const float am   = wave_max_f(a);
        const float e    = act ? expf(a - am) : 0.0f;
        const float esum = wave_sum_f(e);
        const float pw   = e / esum;

        const float m2  = fmaxf(wave_max_f(sj), sdiag);
        const float ex  = act ? expf(sj - m2) : 0.0f;
        const float lse = m2 + logf(wave_sum_f(ex) + expf(sdiag - m2));

        const float num = wave_sum_f(act ? pw * (sj - lse) : 0.0f) + (sdiag - lse);
        const float den = 1.0f + wave_sum_f(pw);
        if (lane == 0) per_row[row] = -num / den;
    }
}

// ---- final mean over per_row -> out[0] ----
__global__ __launch_bounds__(256)
void reduce_kernel(const float* __restrict__ per_row, float* __restrict__ out, int B) {
    __shared__ float s[4];
    float acc = 0.0f;
    const float4* p = (const float4*)per_row;
    const int n4 = B >> 2;
    for (int i = threadIdx.x; i < n4; i += 256) {
        float4 q = p[i];
        acc += (q.x + q.y) + (q.z + q.w);
    }
    acc = wave_sum_f(acc);
    const int lane = threadIdx.x & 63, wid = threadIdx.x >> 6;
    if (lane == 0) s[wid] = acc;
    __syncthreads();
    if (threadIdx.x == 0) out[0] = (s[0] + s[1] + s[2] + s[3]) / (float)B;
}

extern "C" void kernel_launch(void* const* d_in, const int* in_sizes, int n_in,
                              void* d_out, int out_size, void* d_ws, size_t ws_size,
                              hipStream_t stream) {
    const float* sim  = (const float*)d_in[0];
    const float* mem  = (const float*)d_in[1];
    const int*   knn  = (const int*)d_in[2];
    const float* temp = (const float*)d_in[3];
    float* out     = (float*)d_out;
    float* cent    = (float*)d_ws;                 // B floats
    float* per_row = (float*)d_ws + 4096;          // B floats

    const int B = (int)(std::sqrt((double)in_sizes[0]) + 0.5);
    const int M = in_sizes[1] / B;

    cent_kernel<<<B, 256, 0, stream>>>(mem, cent, M);
    row_loss_kernel<<<B, 256, 0, stream>>>(sim, cent, knn, temp, per_row, B);
    reduce_kernel<<<1, 256, 0, stream>>>(per_row, out, B);
}

// Round 5
// 51.729 us; speedup vs baseline: 1.0775x; 1.0775x over previous
//
#include <hip/hip_runtime.h>
#include <cmath>

// ---------------------------------------------------------------------------
// NeighborAdjustingLoss v6: v5 + issue-path surgery (bit-identical output).
//  (1) rank loop: whole-wave guard -- waves with wid*64 >= n skip the ~47
//      ds_read_b128 broadcast loop entirely (typ. waves 2,3; n ~= 93).
//  (2) cent loads hoisted OUT of the bisection loop (loop-invariant) into
//      16 VGPRs -> bisection iterations are pure-register ballots.
//  (3) sim-row loads issued as one 4-deep burst before key processing.
//  (4) finale: cj gather issued before the min/max fold chain.
// B=4096 (sim BxB), M=8192 (mem BxM), k<=63, fp32.
// ---------------------------------------------------------------------------

#define CAP 256    // candidate capacity; expected ~93 for N(0,1) rows (>17 sigma)
#define MAXIT 40   // u32-key bisection bound (1 pass in practice)

__device__ inline float wave_max_f(float x) {
#pragma unroll
    for (int off = 32; off > 0; off >>= 1) x = fmaxf(x, __shfl_xor(x, off, 64));
    return x;
}
__device__ inline float wave_min_f(float x) {
#pragma unroll
    for (int off = 32; off > 0; off >>= 1) x = fminf(x, __shfl_xor(x, off, 64));
    return x;
}
__device__ inline float wave_sum_f(float x) {
#pragma unroll
    for (int off = 32; off > 0; off >>= 1) x += __shfl_xor(x, off, 64);
    return x;
}
__device__ inline unsigned int wave_min_u32(unsigned int x) {
#pragma unroll
    for (int off = 32; off > 0; off >>= 1) {
        unsigned int o = (unsigned int)__shfl_xor((int)x, off, 64);
        x = (o < x) ? o : x;
    }
    return x;
}

// order-preserving float<->uint key
__device__ inline unsigned int f_to_key(float f) {
    unsigned int u = __float_as_uint(f);
    return u ^ ((u & 0x80000000u) ? 0xFFFFFFFFu : 0x80000000u);
}
__device__ inline float key_to_f(unsigned int key) {
    unsigned int u = key ^ ((key & 0x80000000u) ? 0x80000000u : 0xFFFFFFFFu);
    return __uint_as_float(u);
}

// bits set among lanes strictly below mine
__device__ inline unsigned int lane_prefix(unsigned long long mask) {
    return __builtin_amdgcn_mbcnt_hi((unsigned int)(mask >> 32),
           __builtin_amdgcn_mbcnt_lo((unsigned int)mask, 0u));
}

// ---- centrality = row-mean of memory bank (8 loads in flight) ----
__global__ __launch_bounds__(256)
void cent_kernel(const float* __restrict__ mem, float* __restrict__ cent, int M) {
    __shared__ float s[4];
    const int row = blockIdx.x;
    const float4* p = (const float4*)(mem + (size_t)row * M);
    const int n4 = M >> 2;
    float acc = 0.0f;
    int i = threadIdx.x;
    for (; i + 1792 < n4; i += 2048) {
        float4 q0 = p[i], q1 = p[i + 256], q2 = p[i + 512], q3 = p[i + 768];
        float4 q4 = p[i + 1024], q5 = p[i + 1280], q6 = p[i + 1536], q7 = p[i + 1792];
        acc += ((q0.x + q0.y) + (q0.z + q0.w)) + ((q1.x + q1.y) + (q1.z + q1.w))
             + ((q2.x + q2.y) + (q2.z + q2.w)) + ((q3.x + q3.y) + (q3.z + q3.w))
             + ((q4.x + q4.y) + (q4.z + q4.w)) + ((q5.x + q5.y) + (q5.z + q5.w))
             + ((q6.x + q6.y) + (q6.z + q6.w)) + ((q7.x + q7.y) + (q7.z + q7.w));
    }
    for (; i < n4; i += 256) {
        float4 q = p[i];
        acc += (q.x + q.y) + (q.z + q.w);
    }
    acc = wave_sum_f(acc);
    const int lane = threadIdx.x & 63, wid = threadIdx.x >> 6;
    if (lane == 0) s[wid] = acc;
    __syncthreads();
    if (threadIdx.x == 0) cent[row] = (s[0] + s[1] + s[2] + s[3]) / (float)M;
}

// ---- per-row loss -> per_row[row]. One 256-thread block per row.
//      Requires B==4096, k<=63. ----
__global__ __launch_bounds__(256)
void row_loss_kernel(const float* __restrict__ sim,
                     const float* __restrict__ cent,
                     const int* __restrict__ knn,
                     const float* __restrict__ temp_p,
                     float* __restrict__ per_row, int B) {
    __shared__ __align__(16) unsigned long long cand[CAP];
    __shared__ unsigned long long s_sel[64];
    __shared__ unsigned long long s_p33;
    __shared__ unsigned int s_kmin[4];
    __shared__ float s_cmin[4], s_cmax[4];
    __shared__ float s_cmin2[4], s_cmax2[4];
    __shared__ unsigned int s_wcnt[4];
    __shared__ float s_diag;

    const int row = blockIdx.x, tid = threadIdx.x;
    const int lane = tid & 63, wid = tid >> 6;
    const int   k    = knn[0];
    const float temp = temp_p[0];

    // --- (3) burst-issue row loads + cent loads (8 loads in flight) ---
    const float4* rp = (const float4*)(sim + (size_t)row * B);
    const float4* cp = (const float4*)cent;
    float4 q0 = rp[tid], q1 = rp[256 + tid], q2 = rp[512 + tid], q3 = rp[768 + tid];
    float4 v0 = cp[tid], v1 = cp[256 + tid], v2 = cp[512 + tid], v3 = cp[768 + tid];

    // --- keys (order-preserving); diag -> key 0 ---
    unsigned int keys[16];
    float cv[16];
    unsigned int kmin = 0xFFFFFFFFu;
    {
        float t[16] = {q0.x, q0.y, q0.z, q0.w, q1.x, q1.y, q1.z, q1.w,
                       q2.x, q2.y, q2.z, q2.w, q3.x, q3.y, q3.z, q3.w};
        float c[16] = {v0.x, v0.y, v0.z, v0.w, v1.x, v1.y, v1.z, v1.w,
                       v2.x, v2.y, v2.z, v2.w, v3.x, v3.y, v3.z, v3.w};
#pragma unroll
        for (int c4i = 0; c4i < 4; ++c4i) {
#pragma unroll
            for (int m = 0; m < 4; ++m) {
                const int e = c4i * 4 + m;
                const int j = c4i * 1024 + tid * 4 + m;
                unsigned int key = f_to_key(t[e]);
                if (j == row) { s_diag = t[e]; key = 0u; }
                else if (key < kmin) kmin = key;
                keys[e] = key;
                cv[e] = c[e];
            }
        }
    }
    { unsigned int w = wave_min_u32(kmin); if (lane == 0) s_kmin[wid] = w; }

    // --- (2) bisection: pure-register ballot counting + cent min/max over
    //     non-candidates. First-guess threshold 2.0 -> 1 pass w.p. ~1. ---
    unsigned int keyT = f_to_key(2.0f), loK = 0u, hiK = 0xFFFFFFFFu, cnt = 0;
    const unsigned int need = (unsigned int)k + 1u;
    for (int it = 0; it < MAXIT; ++it) {
        float cmin = INFINITY, cmax = -INFINITY;
        unsigned int wvCnt = 0;
#pragma unroll
        for (int e = 0; e < 16; ++e) {
            const unsigned int key = keys[e];
            const bool p = (key > keyT);
            const unsigned long long mask = __ballot(p);
            wvCnt += (unsigned int)__popcll(mask);
            if (!p && key != 0u) {       // diag (key==0) excluded everywhere
                cmin = fminf(cmin, cv[e]);
                cmax = fmaxf(cmax, cv[e]);
            }
        }
        { float a = wave_min_f(cmin), b = wave_max_f(cmax);
          if (lane == 0) { s_cmin[wid] = a; s_cmax[wid] = b; s_wcnt[wid] = wvCnt; } }
        __syncthreads();                    // counts/minmax visible
        cnt = s_wcnt[0] + s_wcnt[1] + s_wcnt[2] + s_wcnt[3];
        if (cnt >= need && cnt <= CAP) break;
        if (it == MAXIT - 1) break;
        if (cnt < need) { hiK = keyT; keyT = loK + ((keyT - loK) >> 1); }
        else            { loK = keyT; keyT = keyT + ((hiK - keyT) >> 1); }
        __syncthreads();                    // WAR: reads done before rewrite
    }

    // --- write pass: deterministic compaction via mbcnt prefix ---
    {
        unsigned int base = 0;
#pragma unroll
        for (int w = 0; w < 4; ++w) if (w < wid) base += s_wcnt[w];
        unsigned int run = 0;
#pragma unroll
        for (int e = 0; e < 16; ++e) {
            const unsigned int key = keys[e];
            const bool p = (key > keyT);
            const unsigned long long mask = __ballot(p);
            if (p) {
                const unsigned int pos = base + run + lane_prefix(mask);
                if (pos < CAP)
                    cand[pos] = ((unsigned long long)key << 32) |
                                (unsigned long long)(0xFFFFFFFFu -
                                    (unsigned int)((e >> 2) * 1024 + tid * 4 + (e & 3)));
            }
            run += (unsigned int)__popcll(mask);
        }
        if (tid == 0) s_p33 = ((unsigned long long)1u) << 32;
        __syncthreads();                    // cand/s_p33 visible
    }

    // --- (1) block-wide exact rank with whole-wave guard:
    //     thread t owns cand[t]; waves with wid*64 >= n skip entirely ---
    {
        const unsigned int n = min(cnt, (unsigned int)CAP);
        const unsigned int uk = (unsigned int)k;
        float cmin2 = INFINITY, cmax2 = -INFINITY;
        if ((unsigned int)(wid << 6) < n) {
            unsigned long long own = 0ull;
            if ((unsigned int)tid < n) own = cand[tid];
            unsigned int r = 0;
            const ulonglong2* c2 = (const ulonglong2*)cand;   // broadcast b128
            const unsigned int nq = n >> 2;
            for (unsigned int o = 0; o < nq; ++o) {
                ulonglong2 a0 = c2[2 * o], a1 = c2[2 * o + 1];
                r += (a0.x > own) ? 1u : 0u; r += (a0.y > own) ? 1u : 0u;
                r += (a1.x > own) ? 1u : 0u; r += (a1.y > own) ? 1u : 0u;
            }
            for (unsigned int i = nq << 2; i < n; ++i)
                r += (cand[i] > own) ? 1u : 0u;

            // rank<k: selected; rank==k: (k+1)-th largest (mx_s);
            // rank>=k: re-enters centrality min/max
            if ((unsigned int)tid < n) {
                if (r < uk) s_sel[r] = own;
                else if (r == uk) s_p33 = own;
                if (r >= uk) {
                    const int jj = (int)(0xFFFFFFFFu - (unsigned int)own);
                    const float cvv = cent[jj];
                    cmin2 = fminf(cmin2, cvv);
                    cmax2 = fmaxf(cmax2, cvv);
                }
            }
        }
        cmin2 = wave_min_f(cmin2);
        cmax2 = wave_max_f(cmax2);
        if (lane == 0) { s_cmin2[wid] = cmin2; s_cmax2[wid] = cmax2; }
        __syncthreads();                    // s_sel/s_p33/s_cmin2 visible
    }
    if (wid != 0) return;                   // waves 1-3 done

    // --- wave 0: finale (math identical to validated kernel) ---
    {
        // (4) issue the scattered cj gather before the fold chains
        const float sdiag = s_diag;
        const bool  act = (lane < k);
        const unsigned long long sel = act ? s_sel[lane] : 0ull;
        const float sj = act ? key_to_f((unsigned int)(sel >> 32)) : -INFINITY;
        const int   j  = act ? (int)(0xFFFFFFFFu - (unsigned int)sel) : 0;
        const float cj = cent[j];

        const float mn_c = fminf(
            fminf(fminf(s_cmin2[0], s_cmin2[1]), fminf(s_cmin2[2], s_cmin2[3])),
            fminf(fminf(s_cmin[0], s_cmin[1]), fminf(s_cmin[2], s_cmin[3])));
        const float mx_c = fmaxf(
            fmaxf(fmaxf(s_cmax2[0], s_cmax2[1]), fmaxf(s_cmax2[2], s_cmax2[3])),
            fmaxf(fmaxf(s_cmax[0], s_cmax[1]), fmaxf(s_cmax[2], s_cmax[3])));
        const unsigned int kminb =
            min(min(s_kmin[0], s_kmin[1]), min(s_kmin[2], s_kmin[3]));
        const float mn_s = key_to_f(kminb);
        const float mx_s = key_to_f((unsigned int)(s_p33 >> 32));

        float a = -INFINITY;
        if (act) {
            const float ns = (sj - mn_s) / (mx_s - mn_s);
            const float nc = (cj - mn_c) / (mx_c - mn_c);
            a = (ns - nc) * temp;
        }
        const float am   = wave_max_f(a);
        const float e    = act ? expf(a - am) : 0.0f;
        const float esum = wave_sum_f(e);
        const float pw   = e / esum;

        const float m2  = fmaxf(wave_max_f(sj), sdiag);
        const float ex  = act ? expf(sj - m2) : 0.0f;
        const float lse = m2 + logf(wave_sum_f(ex) + expf(sdiag - m2));

        const float num = wave_sum_f(act ? pw * (sj - lse) : 0.0f) + (sdiag - lse);
        const float den = 1.0f + wave_sum_f(pw);
        if (lane == 0) per_row[row] = -num / den;
    }
}

// ---- final mean over per_row -> out[0] ----
__global__ __launch_bounds__(256)
void reduce_kernel(const float* __restrict__ per_row, float* __restrict__ out, int B) {
    __shared__ float s[4];
    float acc = 0.0f;
    const float4* p = (const float4*)per_row;
    const int n4 = B >> 2;
    for (int i = threadIdx.x; i < n4; i += 256) {
        float4 q = p[i];
        acc += (q.x + q.y) + (q.z + q.w);
    }
    acc = wave_sum_f(acc);
    const int lane = threadIdx.x & 63, wid = threadIdx.x >> 6;
    if (lane == 0) s[wid] = acc;
    __syncthreads();
    if (threadIdx.x == 0) out[0] = (s[0] + s[1] + s[2] + s[3]) / (float)B;
}

extern "C" void kernel_launch(void* const* d_in, const int* in_sizes, int n_in,
                              void* d_out, int out_size, void* d_ws, size_t ws_size,
                              hipStream_t stream) {
    const float* sim  = (const float*)d_in[0];
    const float* mem  = (const float*)d_in[1];
    const int*   knn  = (const int*)d_in[2];
    const float* temp = (const float*)d_in[3];
    float* out     = (float*)d_out;
    float* cent    = (float*)d_ws;                 // B floats
    float* per_row = (float*)d_ws + 4096;          // B floats

    const int B = (int)(std::sqrt((double)in_sizes[0]) + 0.5);
    const int M = in_sizes[1] / B;

    cent_kernel<<<B, 256, 0, stream>>>(mem, cent, M);
    row_loss_kernel<<<B, 256, 0, stream>>>(sim, cent, knn, temp, per_row, B);
    reduce_kernel<<<1, 256, 0, stream>>>(per_row, out, B);
}

// Round 7
// 50.630 us; speedup vs baseline: 1.1009x; 1.0217x over previous
//
#include <hip/hip_runtime.h>
#include <cmath>

// ---------------------------------------------------------------------------
// NeighborAdjustingLoss v7 (resubmit; round-6 bench died to infra before
// execution): v6 + candidate-count cut + fused gather.
//  (1) threshold 2.0 -> 2.2: E[n] 93 -> ~57. Halves rank DS reads, LDS
//      candidate writes, rank-tail cent gathers; rank is single-wave.
//      Register-only bisection fallback keeps it exact (P~6e-4/row).
//  (2) count+write FUSED into one pass: candidates land in per-wave 64-slot
//      LDS segments at ballot-prefix positions; kills the second 16-ballot
//      pass and one barrier. Exact compacted fallback if counts misbehave.
//  (3) finale: m2 = max(sj) taken from rank-0 candidate (s_sel[0]) instead
//      of a 6-shfl wave reduction (same float, max is order-free).
// Output bit-identical to v4/v5/v6. B=4096, M=8192, k<=63, fp32.
// ---------------------------------------------------------------------------

#define CAP 256    // total candidate capacity (4 segments x 64)
#define MAXIT 40   // u32-key bisection bound for the rare fallback

__device__ inline float wave_max_f(float x) {
#pragma unroll
    for (int off = 32; off > 0; off >>= 1) x = fmaxf(x, __shfl_xor(x, off, 64));
    return x;
}
__device__ inline float wave_min_f(float x) {
#pragma unroll
    for (int off = 32; off > 0; off >>= 1) x = fminf(x, __shfl_xor(x, off, 64));
    return x;
}
__device__ inline float wave_sum_f(float x) {
#pragma unroll
    for (int off = 32; off > 0; off >>= 1) x += __shfl_xor(x, off, 64);
    return x;
}
__device__ inline unsigned int wave_min_u32(unsigned int x) {
#pragma unroll
    for (int off = 32; off > 0; off >>= 1) {
        unsigned int o = (unsigned int)__shfl_xor((int)x, off, 64);
        x = (o < x) ? o : x;
    }
    return x;
}

// order-preserving float<->uint key
__device__ inline unsigned int f_to_key(float f) {
    unsigned int u = __float_as_uint(f);
    return u ^ ((u & 0x80000000u) ? 0xFFFFFFFFu : 0x80000000u);
}
__device__ inline float key_to_f(unsigned int key) {
    unsigned int u = key ^ ((key & 0x80000000u) ? 0x80000000u : 0xFFFFFFFFu);
    return __uint_as_float(u);
}

// bits set among lanes strictly below mine
__device__ inline unsigned int lane_prefix(unsigned long long mask) {
    return __builtin_amdgcn_mbcnt_hi((unsigned int)(mask >> 32),
           __builtin_amdgcn_mbcnt_lo((unsigned int)mask, 0u));
}

// ---- centrality = row-mean of memory bank (8 loads in flight) ----
__global__ __launch_bounds__(256)
void cent_kernel(const float* __restrict__ mem, float* __restrict__ cent, int M) {
    __shared__ float s[4];
    const int row = blockIdx.x;
    const float4* p = (const float4*)(mem + (size_t)row * M);
    const int n4 = M >> 2;
    float acc = 0.0f;
    int i = threadIdx.x;
    for (; i + 1792 < n4; i += 2048) {
        float4 q0 = p[i], q1 = p[i + 256], q2 = p[i + 512], q3 = p[i + 768];
        float4 q4 = p[i + 1024], q5 = p[i + 1280], q6 = p[i + 1536], q7 = p[i + 1792];
        acc += ((q0.x + q0.y) + (q0.z + q0.w)) + ((q1.x + q1.y) + (q1.z + q1.w))
             + ((q2.x + q2.y) + (q2.z + q2.w)) + ((q3.x + q3.y) + (q3.z + q3.w))
             + ((q4.x + q4.y) + (q4.z + q4.w)) + ((q5.x + q5.y) + (q5.z + q5.w))
             + ((q6.x + q6.y) + (q6.z + q6.w)) + ((q7.x + q7.y) + (q7.z + q7.w));
    }
    for (; i < n4; i += 256) {
        float4 q = p[i];
        acc += (q.x + q.y) + (q.z + q.w);
    }
    acc = wave_sum_f(acc);
    const int lane = threadIdx.x & 63, wid = threadIdx.x >> 6;
    if (lane == 0) s[wid] = acc;
    __syncthreads();
    if (threadIdx.x == 0) cent[row] = (s[0] + s[1] + s[2] + s[3]) / (float)M;
}

// ---- per-row loss -> per_row[row]. One 256-thread block per row.
//      Requires B==4096, k<=63. ----
__global__ __launch_bounds__(256)
void row_loss_kernel(const float* __restrict__ sim,
                     const float* __restrict__ cent,
                     const int* __restrict__ knn,
                     const float* __restrict__ temp_p,
                     float* __restrict__ per_row, int B) {
    __shared__ __align__(16) unsigned long long cand[CAP];   // 4 x 64 segments
    __shared__ unsigned long long s_sel[64];
    __shared__ unsigned long long s_p33;
    __shared__ unsigned int s_kmin[4];
    __shared__ float s_cmin[4], s_cmax[4];
    __shared__ float s_cmin2[4], s_cmax2[4];
    __shared__ unsigned int s_wcnt[4];
    __shared__ float s_diag;

    const int row = blockIdx.x, tid = threadIdx.x;
    const int lane = tid & 63, wid = tid >> 6;
    const int   k    = knn[0];
    const float temp = temp_p[0];

    // --- burst-issue row loads + cent loads (8 loads in flight) ---
    const float4* rp = (const float4*)(sim + (size_t)row * B);
    const float4* cp = (const float4*)cent;
    float4 q0 = rp[tid], q1 = rp[256 + tid], q2 = rp[512 + tid], q3 = rp[768 + tid];
    float4 v0 = cp[tid], v1 = cp[256 + tid], v2 = cp[512 + tid], v3 = cp[768 + tid];

    // --- keys (order-preserving); diag -> key 0 ---
    unsigned int keys[16];
    float cv[16];
    unsigned int kmin = 0xFFFFFFFFu;
    {
        float t[16] = {q0.x, q0.y, q0.z, q0.w, q1.x, q1.y, q1.z, q1.w,
                       q2.x, q2.y, q2.z, q2.w, q3.x, q3.y, q3.z, q3.w};
        float c[16] = {v0.x, v0.y, v0.z, v0.w, v1.x, v1.y, v1.z, v1.w,
                       v2.x, v2.y, v2.z, v2.w, v3.x, v3.y, v3.z, v3.w};
#pragma unroll
        for (int c4i = 0; c4i < 4; ++c4i) {
#pragma unroll
            for (int m = 0; m < 4; ++m) {
                const int e = c4i * 4 + m;
                const int j = c4i * 1024 + tid * 4 + m;
                unsigned int key = f_to_key(t[e]);
                if (j == row) { s_diag = t[e]; key = 0u; }
                else if (key < kmin) kmin = key;
                keys[e] = key;
                cv[e] = c[e];
            }
        }
    }
    { unsigned int w = wave_min_u32(kmin); if (lane == 0) s_kmin[wid] = w; }
    if (tid == 0) s_p33 = ((unsigned long long)1u) << 32;

    // --- fused count+write pass @ threshold 2.2 (E[n]~57):
    //     candidates -> per-wave 64-slot segments at ballot-prefix positions;
    //     cent min/max folded over non-candidates. One barrier. ---
    unsigned int keyT = f_to_key(2.2f), cnt = 0;
    const unsigned int need = (unsigned int)k + 1u;
    {
        float cmin = INFINITY, cmax = -INFINITY;
        unsigned int wvCnt = 0;
#pragma unroll
        for (int e = 0; e < 16; ++e) {
            const unsigned int key = keys[e];
            const bool p = (key > keyT);
            const unsigned long long mask = __ballot(p);
            if (p) {
                const unsigned int pos = wvCnt + lane_prefix(mask);
                if (pos < 64u)
                    cand[(wid << 6) + pos] = ((unsigned long long)key << 32) |
                        (unsigned long long)(0xFFFFFFFFu -
                            (unsigned int)((e >> 2) * 1024 + tid * 4 + (e & 3)));
            } else if (key != 0u) {          // diag (key==0) excluded everywhere
                cmin = fminf(cmin, cv[e]);
                cmax = fmaxf(cmax, cv[e]);
            }
            wvCnt += (unsigned int)__popcll(mask);
        }
        float a = wave_min_f(cmin), b = wave_max_f(cmax);
        if (lane == 0) { s_cmin[wid] = a; s_cmax[wid] = b; s_wcnt[wid] = wvCnt; }
    }
    __syncthreads();                         // cand/wcnt/minmax visible

    unsigned int c0 = s_wcnt[0], c1 = s_wcnt[1], c2 = s_wcnt[2], c3 = s_wcnt[3];
    cnt = c0 + c1 + c2 + c3;
    bool cntOK = (cnt >= need && cnt <= CAP);
    bool seg = cntOK && (c0 <= 64u) && (c1 <= 64u) && (c2 <= 64u) && (c3 <= 64u);

    // --- rare fallback: register-only bisection + compacted write pass ---
    if (!seg) {
        if (!cntOK) {
            unsigned int loK = 0u, hiK = 0xFFFFFFFFu;
            for (int it = 0; it < MAXIT; ++it) {
                if (cnt < need) { hiK = keyT; keyT = loK + ((keyT - loK) >> 1); }
                else            { loK = keyT; keyT = keyT + ((hiK - keyT) >> 1); }
                __syncthreads();             // WAR on s_wcnt/s_cmin
                float cmin = INFINITY, cmax = -INFINITY;
                unsigned int wvCnt = 0;
#pragma unroll
                for (int e = 0; e < 16; ++e) {
                    const unsigned int key = keys[e];
                    const bool p = (key > keyT);
                    wvCnt += (unsigned int)__popcll(__ballot(p));
                    if (!p && key != 0u) {
                        cmin = fminf(cmin, cv[e]);
                        cmax = fmaxf(cmax, cv[e]);
                    }
                }
                float a = wave_min_f(cmin), b = wave_max_f(cmax);
                if (lane == 0) { s_cmin[wid] = a; s_cmax[wid] = b; s_wcnt[wid] = wvCnt; }
                __syncthreads();
                cnt = s_wcnt[0] + s_wcnt[1] + s_wcnt[2] + s_wcnt[3];
                if (cnt >= need && cnt <= CAP) break;
            }
            c0 = s_wcnt[0]; c1 = s_wcnt[1]; c2 = s_wcnt[2]; c3 = s_wcnt[3];
        }
        // compacted write pass (flat [0, cnt))
        unsigned int base = 0;
#pragma unroll
        for (int w = 0; w < 4; ++w) if (w < wid) base += s_wcnt[w];
        unsigned int run = 0;
#pragma unroll
        for (int e = 0; e < 16; ++e) {
            const unsigned int key = keys[e];
            const bool p = (key > keyT);
            const unsigned long long mask = __ballot(p);
            if (p) {
                const unsigned int pos = base + run + lane_prefix(mask);
                if (pos < CAP)
                    cand[pos] = ((unsigned long long)key << 32) |
                        (unsigned long long)(0xFFFFFFFFu -
                            (unsigned int)((e >> 2) * 1024 + tid * 4 + (e & 3)));
            }
            run += (unsigned int)__popcll(mask);
        }
        __syncthreads();                     // compacted cand visible
    }

    // --- block-wide exact rank (typically wave 0 only; n ~= 57) ---
    {
        const unsigned int n = min(cnt, (unsigned int)CAP);
        const unsigned int uk = (unsigned int)k;
        const unsigned int e1 = c0, e2 = c0 + c1, e3 = c0 + c1 + c2;
        float cmin2 = INFINITY, cmax2 = -INFINITY;
        if ((unsigned int)(wid << 6) < n) {
            // ownership: thread t owns the t-th valid candidate
            unsigned long long own = 0ull;
            const unsigned int t = (unsigned int)tid;
            if (t < n) {
                if (seg) {
                    unsigned int w, off;
                    if (t < e1)      { w = 0u; off = t; }
                    else if (t < e2) { w = 1u; off = t - e1; }
                    else if (t < e3) { w = 2u; off = t - e2; }
                    else             { w = 3u; off = t - e3; }
                    own = cand[(w << 6) + off];
                } else {
                    own = cand[t];
                }
            }
            unsigned int r = 0;
            if (seg) {
#pragma unroll
                for (int w = 0; w < 4; ++w) {
                    const unsigned int len = s_wcnt[w];
                    const unsigned int b = (unsigned int)(w << 6);
                    for (unsigned int i = 0; i < len; ++i)
                        r += (cand[b + i] > own) ? 1u : 0u;
                }
            } else {
                for (unsigned int i = 0; i < n; ++i)
                    r += (cand[i] > own) ? 1u : 0u;
            }
            // rank<k: selected; rank==k: (k+1)-th largest (mx_s);
            // rank>=k: re-enters centrality min/max
            if (t < n) {
                if (r < uk) s_sel[r] = own;
                else if (r == uk) s_p33 = own;
                if (r >= uk) {
                    const int jj = (int)(0xFFFFFFFFu - (unsigned int)own);
                    const float cvv = cent[jj];
                    cmin2 = fminf(cmin2, cvv);
                    cmax2 = fmaxf(cmax2, cvv);
                }
            }
        }
        cmin2 = wave_min_f(cmin2);
        cmax2 = wave_max_f(cmax2);
        if (lane == 0) { s_cmin2[wid] = cmin2; s_cmax2[wid] = cmax2; }
        __syncthreads();                     // s_sel/s_p33/s_cmin2 visible
    }
    if (wid != 0) return;                    // waves 1-3 done

    // --- wave 0: finale (math identical to validated kernel) ---
    {
        const float sdiag = s_diag;
        const bool  act = (lane < k);
        const unsigned long long sel = act ? s_sel[lane] : 0ull;
        const float sj = act ? key_to_f((unsigned int)(sel >> 32)) : -INFINITY;
        const int   j  = act ? (int)(0xFFFFFFFFu - (unsigned int)sel) : 0;
        const float cj = cent[j];

        const float mn_c = fminf(
            fminf(fminf(s_cmin2[0], s_cmin2[1]), fminf(s_cmin2[2], s_cmin2[3])),
            fminf(fminf(s_cmin[0], s_cmin[1]), fminf(s_cmin[2], s_cmin[3])));
        const float mx_c = fmaxf(
            fmaxf(fmaxf(s_cmax2[0], s_cmax2[1]), fmaxf(s_cmax2[2], s_cmax2[3])),
            fmaxf(fmaxf(s_cmax[0], s_cmax[1]), fmaxf(s_cmax[2], s_cmax[3])));
        const unsigned int kminb =
            min(min(s_kmin[0], s_kmin[1]), min(s_kmin[2], s_kmin[3]));
        const float mn_s = key_to_f(kminb);
        const float mx_s = key_to_f((unsigned int)(s_p33 >> 32));

        float a = -INFINITY;
        if (act) {
            const float ns = (sj - mn_s) / (mx_s - mn_s);
            const float nc = (cj - mn_c) / (mx_c - mn_c);
            a = (ns - nc) * temp;
        }
        const float am   = wave_max_f(a);
        const float e    = act ? expf(a - am) : 0.0f;
        const float esum = wave_sum_f(e);
        const float pw   = e / esum;

        // m2 = max(sj) = rank-0 candidate's value (exact, order-free max)
        const float m2  = fmaxf(key_to_f((unsigned int)(s_sel[0] >> 32)), sdiag);
        const float ex  = act ? expf(sj - m2) : 0.0f;
        const float lse = m2 + logf(wave_sum_f(ex) + expf(sdiag - m2));

        const float num = wave_sum_f(act ? pw * (sj - lse) : 0.0f) + (sdiag - lse);
        const float den = 1.0f + wave_sum_f(pw);
        if (lane == 0) per_row[row] = -num / den;
    }
}

// ---- final mean over per_row -> out[0] ----
__global__ __launch_bounds__(256)
void reduce_kernel(const float* __restrict__ per_row, float* __restrict__ out, int B) {
    __shared__ float s[4];
    float acc = 0.0f;
    const float4* p = (const float4*)per_row;
    const int n4 = B >> 2;
    for (int i = threadIdx.x; i < n4; i += 256) {
        float4 q = p[i];
        acc += (q.x + q.y) + (q.z + q.w);
    }
    acc = wave_sum_f(acc);
    const int lane = threadIdx.x & 63, wid = threadIdx.x >> 6;
    if (lane == 0) s[wid] = acc;
    __syncthreads();
    if (threadIdx.x == 0) out[0] = (s[0] + s[1] + s[2] + s[3]) / (float)B;
}

extern "C" void kernel_launch(void* const* d_in, const int* in_sizes, int n_in,
                              void* d_out, int out_size, void* d_ws, size_t ws_size,
                              hipStream_t stream) {
    const float* sim  = (const float*)d_in[0];
    const float* mem  = (const float*)d_in[1];
    const int*   knn  = (const int*)d_in[2];
    const float* temp = (const float*)d_in[3];
    float* out     = (float*)d_out;
    float* cent    = (float*)d_ws;                 // B floats
    float* per_row = (float*)d_ws + 4096;          // B floats

    const int B = (int)(std::sqrt((double)in_sizes[0]) + 0.5);
    const int M = in_sizes[1] / B;

    cent_kernel<<<B, 256, 0, stream>>>(mem, cent, M);
    row_loss_kernel<<<B, 256, 0, stream>>>(sim, cent, knn, temp, per_row, B);
    reduce_kernel<<<1, 256, 0, stream>>>(per_row, out, B);
}

// Round 8
// 49.936 us; speedup vs baseline: 1.1162x; 1.0139x over previous
//
#include <hip/hip_runtime.h>
#include <cmath>

// ---------------------------------------------------------------------------
// NeighborAdjustingLoss v8: wave-per-row, zero-__syncthreads row_loss.
// Diagnosis: v0-v7 counters (VALUBusy 20%, occ 60%, runtime independent of
// memory tier) show the post-load phases are block-serialized on wave 0
// behind barriers. v8 gives each 64-lane wave a full row: fused stream pass
// (ballot-gather -> wave-private LDS segment + inline cent min/max), fully
// unrolled b128 broadcast rank, wave-local finale. 4 independent rows/block,
// whole grid resident, no block barriers at all.
// Bit-identical output to v4-v7 (same threshold/candidate sets, exact
// min/max/rank, identical reduction shapes). B=4096, M=8192, k<=63, fp32.
// ---------------------------------------------------------------------------

#define CAPW 128   // per-wave candidate capacity (E[n]~57 @ thr 2.2; P(n>128)~0)
#define MAXIT 40   // u32-key bisection bound for the rare exact fallback

__device__ inline float wave_max_f(float x) {
#pragma unroll
    for (int off = 32; off > 0; off >>= 1) x = fmaxf(x, __shfl_xor(x, off, 64));
    return x;
}
__device__ inline float wave_min_f(float x) {
#pragma unroll
    for (int off = 32; off > 0; off >>= 1) x = fminf(x, __shfl_xor(x, off, 64));
    return x;
}
__device__ inline float wave_sum_f(float x) {
#pragma unroll
    for (int off = 32; off > 0; off >>= 1) x += __shfl_xor(x, off, 64);
    return x;
}
__device__ inline unsigned int wave_min_u32(unsigned int x) {
#pragma unroll
    for (int off = 32; off > 0; off >>= 1) {
        unsigned int o = (unsigned int)__shfl_xor((int)x, off, 64);
        x = (o < x) ? o : x;
    }
    return x;
}
__device__ inline unsigned int wave_max_u32(unsigned int x) {
#pragma unroll
    for (int off = 32; off > 0; off >>= 1) {
        unsigned int o = (unsigned int)__shfl_xor((int)x, off, 64);
        x = (o > x) ? o : x;
    }
    return x;
}

// order-preserving float<->uint key
__device__ inline unsigned int f_to_key(float f) {
    unsigned int u = __float_as_uint(f);
    return u ^ ((u & 0x80000000u) ? 0xFFFFFFFFu : 0x80000000u);
}
__device__ inline float key_to_f(unsigned int key) {
    unsigned int u = key ^ ((key & 0x80000000u) ? 0x80000000u : 0xFFFFFFFFu);
    return __uint_as_float(u);
}

// bits set among lanes strictly below mine
__device__ inline unsigned int lane_prefix(unsigned long long mask) {
    return __builtin_amdgcn_mbcnt_hi((unsigned int)(mask >> 32),
           __builtin_amdgcn_mbcnt_lo((unsigned int)mask, 0u));
}

// ---- centrality = row-mean of memory bank (8 loads in flight) ----
__global__ __launch_bounds__(256)
void cent_kernel(const float* __restrict__ mem, float* __restrict__ cent, int M) {
    __shared__ float s[4];
    const int row = blockIdx.x;
    const float4* p = (const float4*)(mem + (size_t)row * M);
    const int n4 = M >> 2;
    float acc = 0.0f;
    int i = threadIdx.x;
    for (; i + 1792 < n4; i += 2048) {
        float4 q0 = p[i], q1 = p[i + 256], q2 = p[i + 512], q3 = p[i + 768];
        float4 q4 = p[i + 1024], q5 = p[i + 1280], q6 = p[i + 1536], q7 = p[i + 1792];
        acc += ((q0.x + q0.y) + (q0.z + q0.w)) + ((q1.x + q1.y) + (q1.z + q1.w))
             + ((q2.x + q2.y) + (q2.z + q2.w)) + ((q3.x + q3.y) + (q3.z + q3.w))
             + ((q4.x + q4.y) + (q4.z + q4.w)) + ((q5.x + q5.y) + (q5.z + q5.w))
             + ((q6.x + q6.y) + (q6.z + q6.w)) + ((q7.x + q7.y) + (q7.z + q7.w));
    }
    for (; i < n4; i += 256) {
        float4 q = p[i];
        acc += (q.x + q.y) + (q.z + q.w);
    }
    acc = wave_sum_f(acc);
    const int lane = threadIdx.x & 63, wid = threadIdx.x >> 6;
    if (lane == 0) s[wid] = acc;
    __syncthreads();
    if (threadIdx.x == 0) cent[row] = (s[0] + s[1] + s[2] + s[3]) / (float)M;
}

// ---- per-row loss: ONE WAVE per row, 4 rows per 256-thread block.
//      No __syncthreads. Requires B==4096, k<=63. ----
__global__ __launch_bounds__(256)
void row_loss_kernel(const float* __restrict__ sim,
                     const float* __restrict__ cent,
                     const int* __restrict__ knn,
                     const float* __restrict__ temp_p,
                     float* __restrict__ per_row, int B) {
    __shared__ __align__(16) unsigned long long cand[4][CAPW];  // per-wave
    __shared__ __align__(16) unsigned long long ssel[4][64];    // per-wave

    const int tid = threadIdx.x, lane = tid & 63, wid = tid >> 6;
    const int row = (blockIdx.x << 2) + wid;
    const int   k    = knn[0];
    const float temp = temp_p[0];
    const unsigned int uk = (unsigned int)k, need = uk + 1u;

    const float4* rp = (const float4*)(sim + (size_t)row * B);
    const float4* cp = (const float4*)cent;
    unsigned long long* mycand = cand[wid];
    unsigned long long* mysel  = ssel[wid];

    float cmin, cmax, dval;
    unsigned int kmin, wcnt;

    // fused stream pass over the row: threshold gather (optionally writing
    // candidates to the wave segment), cent min/max over non-candidates,
    // row-min key, diag value. 64 elems/lane; 8 loads in flight per group.
    auto pass = [&](unsigned int kT, bool wr) {
        cmin = INFINITY; cmax = -INFINITY;
        kmin = 0xFFFFFFFFu; dval = -INFINITY; wcnt = 0u;
        for (int g = 0; g < 4; ++g) {
            float4 sv[4], cw4[4];
#pragma unroll
            for (int u = 0; u < 4; ++u) sv[u] = rp[(g * 4 + u) * 64 + lane];
#pragma unroll
            for (int u = 0; u < 4; ++u) cw4[u] = cp[(g * 4 + u) * 64 + lane];
#pragma unroll
            for (int u = 0; u < 4; ++u) {
                const int c = g * 4 + u;
                const float tv[4] = {sv[u].x, sv[u].y, sv[u].z, sv[u].w};
                const float cw[4] = {cw4[u].x, cw4[u].y, cw4[u].z, cw4[u].w};
#pragma unroll
                for (int m = 0; m < 4; ++m) {
                    const int j = c * 256 + lane * 4 + m;
                    unsigned int key = f_to_key(tv[m]);
                    const bool isd = (j == row);
                    if (isd) { dval = tv[m]; key = 0u; }
                    else if (key < kmin) kmin = key;
                    const bool p = (key > kT);
                    const unsigned long long mask = __ballot(p);
                    if (p) {
                        if (wr) {
                            const unsigned int pos = wcnt + lane_prefix(mask);
                            if (pos < CAPW)
                                mycand[pos] = ((unsigned long long)key << 32) |
                                    (unsigned long long)(0xFFFFFFFFu - (unsigned int)j);
                        }
                    } else if (!isd) {
                        cmin = fminf(cmin, cw[m]);
                        cmax = fmaxf(cmax, cw[m]);
                    }
                    wcnt += (unsigned int)__popcll(mask);
                }
            }
        }
    };

    unsigned int keyT = f_to_key(2.2f);
    pass(keyT, true);
    unsigned int n = wcnt;                    // wave-uniform
    if (n < need || n > CAPW) {               // rare exact fallback (~5e-4/row)
        unsigned int loK = 0u, hiK = 0xFFFFFFFFu;
        for (int it = 0; it < MAXIT; ++it) {
            if (n < need) { hiK = keyT; keyT = loK + ((keyT - loK) >> 1); }
            else          { loK = keyT; keyT = keyT + ((hiK - keyT) >> 1); }
            pass(keyT, false);
            n = wcnt;
            if (n >= need && n <= CAPW) break;
        }
        pass(keyT, true);
        n = wcnt;
        if (n > CAPW) n = CAPW;               // statistical impossibility guard
    }

    // wave-reduce pass results
    const unsigned int kminb = wave_min_u32(kmin);
    const float sdiag = wave_max_f(dval);
    const float cminP = wave_min_f(cmin);
    const float cmaxP = wave_max_f(cmax);

    __builtin_amdgcn_wave_barrier();          // cand writes before rank reads

    // ---- in-wave exact all-pairs rank (n <= CAPW), fully unrolled b128 ----
    unsigned long long own = mycand[lane];    // stale if lane>=n (masked below)
    unsigned long long own2 = 0ull;
    unsigned int r = 0, r2 = 0;
    const ulonglong2* c2 = (const ulonglong2*)mycand;
    if (n <= 64u) {
#pragma unroll
        for (int o = 0; o < 32; ++o) {
            const ulonglong2 pr = c2[o];
            if ((unsigned int)(2 * o)     < n && pr.x > own) ++r;
            if ((unsigned int)(2 * o + 1) < n && pr.y > own) ++r;
        }
    } else {
        own2 = mycand[64 + lane];
#pragma unroll
        for (int o = 0; o < 64; ++o) {
            const ulonglong2 pr = c2[o];
            if ((unsigned int)(2 * o) < n) {
                if (pr.x > own)  ++r;
                if (pr.x > own2) ++r2;
            }
            if ((unsigned int)(2 * o + 1) < n) {
                if (pr.y > own)  ++r;
                if (pr.y > own2) ++r2;
            }
        }
    }

    // selected / p33 / rank-tail cent re-entry
    float cmin2 = INFINITY, cmax2 = -INFINITY;
    unsigned int p33k = 0u;
    if ((unsigned int)lane < n) {
        if (r < uk) mysel[r] = own;
        else if (r == uk) p33k = (unsigned int)(own >> 32);
        if (r >= uk) {
            const int jj = (int)(0xFFFFFFFFu - (unsigned int)own);
            const float cv = cent[jj];
            cmin2 = fminf(cmin2, cv);
            cmax2 = fmaxf(cmax2, cv);
        }
    }
    if (n > 64u) {
        const unsigned int t2 = (unsigned int)lane + 64u;
        if (t2 < n) {
            if (r2 < uk) mysel[r2] = own2;
            else if (r2 == uk) p33k = (unsigned int)(own2 >> 32);
            if (r2 >= uk) {
                const int jj = (int)(0xFFFFFFFFu - (unsigned int)own2);
                const float cv = cent[jj];
                cmin2 = fminf(cmin2, cv);
                cmax2 = fmaxf(cmax2, cv);
            }
        }
    }
    p33k  = wave_max_u32(p33k);
    cmin2 = wave_min_f(cmin2);
    cmax2 = wave_max_f(cmax2);
    __builtin_amdgcn_wave_barrier();          // mysel writes before reads

    const float mn_c = fminf(cmin2, cminP);
    const float mx_c = fmaxf(cmax2, cmaxP);
    const float mn_s = key_to_f(kminb);
    const float mx_s = key_to_f(p33k);

    // ---- finale (math identical to validated v7) ----
    const bool act = (lane < k);
    const unsigned long long sel = act ? mysel[lane] : 0ull;
    const float sj = act ? key_to_f((unsigned int)(sel >> 32)) : -INFINITY;
    const int   j  = act ? (int)(0xFFFFFFFFu - (unsigned int)sel) : 0;
    const float cj = cent[j];

    float a = -INFINITY;
    if (act) {
        const float ns = (sj - mn_s) / (mx_s - mn_s);
        const float nc = (cj - mn_c) / (mx_c - mn_c);
        a = (ns - nc) * temp;
    }
    const float am   = wave_max_f(a);
    const float e    = act ? expf(a - am) : 0.0f;
    const float esum = wave_sum_f(e);
    const float pw   = e / esum;

    // m2 = max(sj) = rank-0 candidate (exact, order-free max)
    const float m2  = fmaxf(key_to_f((unsigned int)(mysel[0] >> 32)), sdiag);
    const float ex  = act ? expf(sj - m2) : 0.0f;
    const float lse = m2 + logf(wave_sum_f(ex) + expf(sdiag - m2));

    const float num = wave_sum_f(act ? pw * (sj - lse) : 0.0f) + (sdiag - lse);
    const float den = 1.0f + wave_sum_f(pw);
    if (lane == 0) per_row[row] = -num / den;
}

// ---- final mean over per_row -> out[0] ----
__global__ __launch_bounds__(256)
void reduce_kernel(const float* __restrict__ per_row, float* __restrict__ out, int B) {
    __shared__ float s[4];
    float acc = 0.0f;
    const float4* p = (const float4*)per_row;
    const int n4 = B >> 2;
    for (int i = threadIdx.x; i < n4; i += 256) {
        float4 q = p[i];
        acc += (q.x + q.y) + (q.z + q.w);
    }
    acc = wave_sum_f(acc);
    const int lane = threadIdx.x & 63, wid = threadIdx.x >> 6;
    if (lane == 0) s[wid] = acc;
    __syncthreads();
    if (threadIdx.x == 0) out[0] = (s[0] + s[1] + s[2] + s[3]) / (float)B;
}

extern "C" void kernel_launch(void* const* d_in, const int* in_sizes, int n_in,
                              void* d_out, int out_size, void* d_ws, size_t ws_size,
                              hipStream_t stream) {
    const float* sim  = (const float*)d_in[0];
    const float* mem  = (const float*)d_in[1];
    const int*   knn  = (const int*)d_in[2];
    const float* temp = (const float*)d_in[3];
    float* out     = (float*)d_out;
    float* cent    = (float*)d_ws;                 // B floats
    float* per_row = (float*)d_ws + 4096;          // B floats

    const int B = (int)(std::sqrt((double)in_sizes[0]) + 0.5);
    const int M = in_sizes[1] / B;

    cent_kernel<<<B, 256, 0, stream>>>(mem, cent, M);
    row_loss_kernel<<<B / 4, 256, 0, stream>>>(sim, cent, knn, temp, per_row, B);
    reduce_kernel<<<1, 256, 0, stream>>>(per_row, out, B);
}